// Round 5
// baseline (344.145 us; speedup 1.0000x reference)
//
#include <hip/hip_runtime.h>
#include <math.h>

#define NPB 64            // nodes per bucket
#define BSH 6
#define MAXNB 1600
#define BIN_CHUNK 8192
#define HIST_CHUNK 16384

typedef __attribute__((ext_vector_type(8))) short bf16x8;
typedef __attribute__((ext_vector_type(4))) float f32x4;

__device__ __forceinline__ unsigned short f2bf(float f){
  unsigned int u = __float_as_uint(f);
  unsigned int r = (u + 0x7FFFu + ((u >> 16) & 1u)) >> 16;   // RNE
  return (unsigned short)r;
}
__device__ __forceinline__ float bf2f(unsigned int b){
  return __uint_as_float(b << 16);
}

// ---------------- CSR build ----------------

__global__ void k_zero(int* __restrict__ p, int n){
  int i = blockIdx.x*256 + threadIdx.x;
  if(i < n) p[i] = 0;
}

__global__ __launch_bounds__(256) void k_bhist(const int* __restrict__ dst, int E,
                                               int* __restrict__ bcnt, int NB){
  __shared__ int l[MAXNB];
  int t = threadIdx.x;
  int base = blockIdx.x*HIST_CHUNK;
  int end = base + HIST_CHUNK; if(end > E) end = E;
  for(int b = t; b < NB; b += 256) l[b] = 0;
  __syncthreads();
  for(int i = base + t; i < end; i += 256) atomicAdd(&l[dst[i] >> BSH], 1);
  __syncthreads();
  for(int b = t; b < NB; b += 256){ int c = l[b]; if(c) atomicAdd(&bcnt[b], c); }
}

__global__ void k_bscan(const int* __restrict__ bcnt, int* __restrict__ bofs,
                        int* __restrict__ bcur, int NB, int E){
  __shared__ int sh[1024];
  int t = threadIdx.x;
  int c0 = (2*t   < NB) ? bcnt[2*t]   : 0;
  int c1 = (2*t+1 < NB) ? bcnt[2*t+1] : 0;
  sh[t] = c0 + c1; __syncthreads();
  for(int off = 1; off < 1024; off <<= 1){
    int v = (t >= off) ? sh[t - off] : 0;
    __syncthreads();
    sh[t] += v;
    __syncthreads();
  }
  int pairEx = sh[t] - (c0 + c1);
  if(2*t   < NB){ bofs[2*t]   = pairEx;      bcur[2*t]   = pairEx; }
  if(2*t+1 < NB){ bofs[2*t+1] = pairEx + c0; bcur[2*t+1] = pairEx + c0; }
  if(t == 0) bofs[NB] = E;
}

__global__ __launch_bounds__(256) void k_binpass(const int* __restrict__ src,
                          const int* __restrict__ dst, int E,
                          int* __restrict__ bcur, unsigned int* __restrict__ binned, int NB){
  __shared__ int lcnt[MAXNB];
  __shared__ int lpos[MAXNB];
  int t = threadIdx.x;
  int base = blockIdx.x * BIN_CHUNK;
  int end = base + BIN_CHUNK; if(end > E) end = E;
  for(int b = t; b < NB; b += 256) lcnt[b] = 0;
  __syncthreads();
  for(int i = base + t; i < end; i += 256)
    atomicAdd(&lcnt[dst[i] >> BSH], 1);
  __syncthreads();
  for(int b = t; b < NB; b += 256){
    int c = lcnt[b];
    lpos[b] = c ? atomicAdd(&bcur[b], c) : 0;
  }
  __syncthreads();
  for(int i = base + t; i < end; i += 256){
    int d = dst[i];
    int b = d >> BSH;
    unsigned int rec = (unsigned int)src[i] | ((unsigned int)(d & (NPB-1)) << 17);
    int p = atomicAdd(&lpos[b], 1);
    binned[p] = rec;
  }
}

__global__ __launch_bounds__(256) void k_bscatter(const unsigned int* __restrict__ binned,
     const int* __restrict__ bofs, int* __restrict__ csr, int* __restrict__ row_ofs,
     float* __restrict__ dinv, int N, int E, int NB){
  __shared__ int lcnt[NPB];
  __shared__ int lofs[NPB];
  __shared__ int lcur[NPB];
  int b = blockIdx.x, t = threadIdx.x;
  int beg = bofs[b], end = bofs[b+1];
  if(t < NPB) lcnt[t] = 0;
  __syncthreads();
  for(int i = beg + t; i < end; i += 256) atomicAdd(&lcnt[binned[i] >> 17], 1);
  __syncthreads();
  if(t < NPB){   // wave 0 only
    int c = lcnt[t];
    int v = c;
    #pragma unroll
    for(int off = 1; off < 64; off <<= 1){
      int nv = __shfl_up(v, off, 64);
      if(t >= off) v += nv;
    }
    int ex = v - c;
    lofs[t] = beg + ex; lcur[t] = 0;
    int node = (b << BSH) + t;
    if(node < N){
      row_ofs[node] = beg + ex;
      dinv[node] = rsqrtf((float)(c + 1));   // +1 self loop
    }
  }
  __syncthreads();
  for(int i = beg + t; i < end; i += 256){
    unsigned int rec = binned[i];
    int dl = rec >> 17;
    int pos = lofs[dl] + atomicAdd(&lcur[dl], 1);
    csr[pos] = (int)(rec & 0x1FFFFu);
  }
  if(b == NB-1 && t == 0) row_ofs[N] = E;
}

// ---------------- GEMM1 (MFMA bf16): g1 = bf16( dinv * (x @ W1) ) ----------------
// 64 nodes/block, wave = 16 nodes x 64 feats, K=128 in 4 mfma steps.
// LDS rows padded to 136 bf16 (272 B, 16B-aligned) -> frag b128 reads conflict-benign.
__global__ __launch_bounds__(256) void k_gemm1(const float* __restrict__ x, const float* __restrict__ W1,
                        const float* __restrict__ dinv, unsigned short* __restrict__ g1, int n){
  __shared__ unsigned short xs[64*136];   // x tile, bf16 [node][k]
  __shared__ unsigned short wt[64*136];   // W1^T,   bf16 [nout][k]
  int tid = threadIdx.x;
  int nodeBase = blockIdx.x*64;
  {
    const float4* x4 = (const float4*)x;
    for(int i = tid; i < 2048; i += 256){
      int node = i >> 5, kg = i & 31;
      float4 v = make_float4(0.f,0.f,0.f,0.f);
      if(nodeBase + node < n) v = x4[(size_t)(nodeBase + node)*32 + kg];
      unsigned p0 = (unsigned)f2bf(v.x) | ((unsigned)f2bf(v.y) << 16);
      unsigned p1 = (unsigned)f2bf(v.z) | ((unsigned)f2bf(v.w) << 16);
      *(uint2*)&xs[node*136 + kg*4] = make_uint2(p0, p1);
    }
  }
  {
    for(int i = tid; i < 2048; i += 256){
      int nn = i >> 5, kq = i & 31;   // k = kq*4..kq*4+3
      unsigned short q0 = f2bf(W1[(kq*4+0)*64 + nn]);
      unsigned short q1 = f2bf(W1[(kq*4+1)*64 + nn]);
      unsigned short q2 = f2bf(W1[(kq*4+2)*64 + nn]);
      unsigned short q3 = f2bf(W1[(kq*4+3)*64 + nn]);
      unsigned p0 = (unsigned)q0 | ((unsigned)q1 << 16);
      unsigned p1 = (unsigned)q2 | ((unsigned)q3 << 16);
      *(uint2*)&wt[nn*136 + kq*4] = make_uint2(p0, p1);
    }
  }
  __syncthreads();

  int w = tid >> 6, lane = tid & 63;
  int ml = lane & 15, q = lane >> 4;
  f32x4 acc0 = {0.f,0.f,0.f,0.f}, acc1 = {0.f,0.f,0.f,0.f},
        acc2 = {0.f,0.f,0.f,0.f}, acc3 = {0.f,0.f,0.f,0.f};
  const unsigned short* arow = &xs[(w*16 + ml)*136 + q*8];
  const unsigned short* brow = &wt[ml*136 + q*8];
  #pragma unroll
  for(int s = 0; s < 4; s++){
    bf16x8 a = *(const bf16x8*)(arow + s*32);
    bf16x8 b0 = *(const bf16x8*)(brow +   0*136 + s*32);
    bf16x8 b1 = *(const bf16x8*)(brow +  16*136 + s*32);
    bf16x8 b2 = *(const bf16x8*)(brow +  32*136 + s*32);
    bf16x8 b3 = *(const bf16x8*)(brow +  48*136 + s*32);
    acc0 = __builtin_amdgcn_mfma_f32_16x16x32_bf16(a, b0, acc0, 0, 0, 0);
    acc1 = __builtin_amdgcn_mfma_f32_16x16x32_bf16(a, b1, acc1, 0, 0, 0);
    acc2 = __builtin_amdgcn_mfma_f32_16x16x32_bf16(a, b2, acc2, 0, 0, 0);
    acc3 = __builtin_amdgcn_mfma_f32_16x16x32_bf16(a, b3, acc3, 0, 0, 0);
  }
  // C/D: col(feature)=lane&15, row(node)=q*4+reg
  int basem = nodeBase + w*16 + q*4;
  #pragma unroll
  for(int r = 0; r < 4; r++){
    int node = basem + r;
    if(node < n){
      float dv = dinv[node];
      g1[(size_t)node*64 +  0 + ml] = f2bf(acc0[r]*dv);
      g1[(size_t)node*64 + 16 + ml] = f2bf(acc1[r]*dv);
      g1[(size_t)node*64 + 32 + ml] = f2bf(acc2[r]*dv);
      g1[(size_t)node*64 + 48 + ml] = f2bf(acc3[r]*dv);
    }
  }
}

// ---------------- agg1: wave/node, 2 feats/lane, 2 rows per load ----------------
// u = bf16( dinv * relu( dinv*(g1_self + sum g1[src]) + b1 ) )
__global__ __launch_bounds__(256) void k_agg1(const unsigned short* __restrict__ g1,
    const int* __restrict__ row_ofs, const int* __restrict__ csr,
    const float* __restrict__ dinv, const float* __restrict__ b1,
    unsigned short* __restrict__ u, int N){
  int wid = threadIdx.x >> 6, lane = threadIdx.x & 63;
  int half = lane >> 5, fl = lane & 31;
  int node = blockIdx.x*4 + wid;
  if(node >= N) return;
  int beg = row_ofs[node], end = row_ofs[node+1];
  const unsigned* g32 = (const unsigned*)g1;
  float alo = 0.f, ahi = 0.f;
  if(half == 0){   // self-loop row, added once
    unsigned v = g32[((unsigned)node << 5) + fl];
    alo = __uint_as_float(v << 16);
    ahi = __uint_as_float(v & 0xFFFF0000u);
  }
  for(int e = beg; e < end; e += 64){
    int cnt = end - e; if(cnt > 64) cnt = 64;
    int idx = (lane < cnt) ? csr[e + lane] : 0;   // one coalesced load = 64 indices
    int pairs = cnt >> 1;
    for(int j = 0; j < pairs; j++){
      int im = __shfl(idx, 2*j + half, 64);
      unsigned v = g32[((unsigned)im << 5) + fl];
      alo += __uint_as_float(v << 16);
      ahi += __uint_as_float(v & 0xFFFF0000u);
    }
    if(cnt & 1){
      int im = __shfl(idx, cnt - 1, 64);
      unsigned v = g32[((unsigned)im << 5) + fl];
      if(half == 0){
        alo += __uint_as_float(v << 16);
        ahi += __uint_as_float(v & 0xFFFF0000u);
      }
    }
  }
  alo += __shfl_xor(alo, 32, 64);
  ahi += __shfl_xor(ahi, 32, 64);
  float dv = dinv[node];
  float2 bb = ((const float2*)b1)[fl];
  float h0 = fmaxf(fmaf(dv, alo, bb.x), 0.f);
  float h1 = fmaxf(fmaf(dv, ahi, bb.y), 0.f);
  if(half == 0){
    unsigned p = (unsigned)f2bf(dv*h0) | ((unsigned)f2bf(dv*h1) << 16);
    *(unsigned*)&u[((size_t)node << 6) + fl*2] = p;
  }
}

// ---------------- GEMM2: g2 = bf16( u @ W2 ), rows padded to 64 ----------------
__global__ __launch_bounds__(256) void k_gemm2(const unsigned short* __restrict__ u,
                        const float* __restrict__ W2, unsigned short* __restrict__ g2, int n){
  __shared__ float hs[64*65];
  __shared__ float ws[64*40];
  int t = threadIdx.x;
  int nodeBase = blockIdx.x*64;
  for(int i = t; i < 2560; i += 256) ws[i] = W2[i];
  for(int i = t; i < 512; i += 256){
    int row = i >> 3, seg = i & 7;
    uint4 v = make_uint4(0,0,0,0);
    if(nodeBase + row < n) v = *(const uint4*)&u[(size_t)(nodeBase + row)*64 + seg*8];
    float* dp = &hs[row*65 + seg*8];
    dp[0]=bf2f(v.x&0xFFFFu); dp[1]=bf2f(v.x>>16);
    dp[2]=bf2f(v.y&0xFFFFu); dp[3]=bf2f(v.y>>16);
    dp[4]=bf2f(v.z&0xFFFFu); dp[5]=bf2f(v.z>>16);
    dp[6]=bf2f(v.w&0xFFFFu); dp[7]=bf2f(v.w>>16);
  }
  __syncthreads();
  int tn = t >> 3, tf = t & 7;
  int n0 = tn*2, f0 = tf*5;
  float a2[2][5] = {{0.f,0.f,0.f,0.f,0.f},{0.f,0.f,0.f,0.f,0.f}};
  #pragma unroll 4
  for(int k = 0; k < 64; k++){
    float a0 = hs[(n0+0)*65 + k];
    float a1 = hs[(n0+1)*65 + k];
    float w0 = ws[k*40+f0+0], w1 = ws[k*40+f0+1], w2 = ws[k*40+f0+2],
          w3 = ws[k*40+f0+3], w4 = ws[k*40+f0+4];
    a2[0][0]+=a0*w0; a2[0][1]+=a0*w1; a2[0][2]+=a0*w2; a2[0][3]+=a0*w3; a2[0][4]+=a0*w4;
    a2[1][0]+=a1*w0; a2[1][1]+=a1*w1; a2[1][2]+=a1*w2; a2[1][3]+=a1*w3; a2[1][4]+=a1*w4;
  }
  #pragma unroll
  for(int i = 0; i < 2; i++){
    int node = nodeBase + n0 + i;
    if(node < n){
      #pragma unroll
      for(int j = 0; j < 5; j++)
        g2[(size_t)node*64 + f0 + j] = f2bf(a2[i][j]);
    }
  }
}

// ---------------- agg2 + bias + log_softmax (2 classes/lane) ----------------
__global__ __launch_bounds__(256) void k_agg2(const unsigned short* __restrict__ g2,
     const int* __restrict__ row_ofs, const int* __restrict__ csr,
     const float* __restrict__ dinv, const float* __restrict__ b2,
     float* __restrict__ out, int N){
  int wid = threadIdx.x >> 6, lane = threadIdx.x & 63;
  int half = lane >> 5, fl = lane & 31;
  int node = blockIdx.x*4 + wid;
  if(node >= N) return;
  int beg = row_ofs[node], end = row_ofs[node+1];
  const unsigned* g32 = (const unsigned*)g2;
  float alo = 0.f, ahi = 0.f;
  if(half == 0){   // self row
    unsigned v = g32[((unsigned)node << 5) + fl];
    alo = __uint_as_float(v << 16);
    ahi = __uint_as_float(v & 0xFFFF0000u);
  }
  for(int e = beg; e < end; e += 64){
    int cnt = end - e; if(cnt > 64) cnt = 64;
    int idx = (lane < cnt) ? csr[e + lane] : 0;
    int pairs = cnt >> 1;
    for(int j = 0; j < pairs; j++){
      int im = __shfl(idx, 2*j + half, 64);
      unsigned v = g32[((unsigned)im << 5) + fl];
      alo += __uint_as_float(v << 16);
      ahi += __uint_as_float(v & 0xFFFF0000u);
    }
    if(cnt & 1){
      int im = __shfl(idx, cnt - 1, 64);
      unsigned v = g32[((unsigned)im << 5) + fl];
      if(half == 0){
        alo += __uint_as_float(v << 16);
        ahi += __uint_as_float(v & 0xFFFF0000u);
      }
    }
  }
  alo += __shfl_xor(alo, 32, 64);
  ahi += __shfl_xor(ahi, 32, 64);
  float dv = dinv[node];
  bool valid = (fl < 20);   // classes 2fl, 2fl+1 < 40
  float vlo = -INFINITY, vhi = -INFINITY;
  if(valid){
    float2 bb = ((const float2*)b2)[fl];
    vlo = fmaf(dv, alo, bb.x);
    vhi = fmaf(dv, ahi, bb.y);
  }
  float m = fmaxf(vlo, vhi);
  #pragma unroll
  for(int off = 32; off > 0; off >>= 1) m = fmaxf(m, __shfl_xor(m, off, 64));
  float ex = (valid && half == 0) ? (expf(vlo - m) + expf(vhi - m)) : 0.f;
  #pragma unroll
  for(int off = 32; off > 0; off >>= 1) ex += __shfl_xor(ex, off, 64);
  float ll = logf(ex);
  if(valid && half == 0){
    float2 o; o.x = vlo - m - ll; o.y = vhi - m - ll;
    *(float2*)&out[(size_t)node*40 + fl*2] = o;
  }
}

// ---------------- launch ----------------

extern "C" void kernel_launch(void* const* d_in, const int* in_sizes, int n_in,
                              void* d_out, int out_size, void* d_ws, size_t ws_size,
                              hipStream_t stream){
  const float* x  = (const float*)d_in[0];
  const int*   ei = (const int*)  d_in[1];
  const float* W1 = (const float*)d_in[2];
  const float* b1 = (const float*)d_in[3];
  const float* W2 = (const float*)d_in[4];
  const float* b2 = (const float*)d_in[5];
  float* out = (float*)d_out;

  int N = in_sizes[0] / 128;        // 100000
  int E = in_sizes[1] / 2;          // 1600000
  const int* src = ei;
  const int* dst = ei + E;
  int NB = (N + NPB - 1) >> BSH;    // 1563

  char* w = (char*)d_ws;
  auto alloc = [&](size_t bytes) -> char* {
    char* p = w;
    w += (bytes + 511) & ~(size_t)511;
    return p;
  };
  int*   bcnt    = (int*)  alloc((size_t)NB*4);
  int*   bofs    = (int*)  alloc((size_t)(NB+1)*4);
  int*   bcur    = (int*)  alloc((size_t)NB*4);
  int*   row_ofs = (int*)  alloc((size_t)(N+1)*4);
  float* dinv    = (float*)alloc((size_t)N*4);
  unsigned int* binned = (unsigned int*)alloc((size_t)E*4);
  int*   csr     = (int*)  alloc((size_t)E*4);
  unsigned short* g1 = (unsigned short*)alloc((size_t)N*64*2);
  unsigned short* u  = (unsigned short*)alloc((size_t)N*64*2);
  unsigned short* g2 = (unsigned short*)alloc((size_t)N*64*2);

  k_zero    <<<(NB+255)/256, 256, 0, stream>>>(bcnt, NB);
  k_bhist   <<<(E+HIST_CHUNK-1)/HIST_CHUNK, 256, 0, stream>>>(dst, E, bcnt, NB);
  k_bscan   <<<1, 1024, 0, stream>>>(bcnt, bofs, bcur, NB, E);
  k_binpass <<<(E+BIN_CHUNK-1)/BIN_CHUNK, 256, 0, stream>>>(src, dst, E, bcur, binned, NB);
  k_bscatter<<<NB, 256, 0, stream>>>(binned, bofs, csr, row_ofs, dinv, N, E, NB);

  k_gemm1   <<<(N+63)/64, 256, 0, stream>>>(x, W1, dinv, g1, N);
  k_agg1    <<<(N+3)/4, 256, 0, stream>>>(g1, row_ofs, csr, dinv, b1, u, N);
  k_gemm2   <<<(N+63)/64, 256, 0, stream>>>(u, W2, g2, N);
  k_agg2    <<<(N+3)/4, 256, 0, stream>>>(g2, row_ofs, csr, dinv, b2, out, N);
}

// Round 6
// 294.022 us; speedup vs baseline: 1.1705x; 1.1705x over previous
//
#include <hip/hip_runtime.h>
#include <math.h>

#define NPB 64            // nodes per bucket
#define BSH 6
#define MAXNB 1600
#define BIN_CHUNK 8192
#define HIST_CHUNK 16384

typedef __attribute__((ext_vector_type(8))) short bf16x8;
typedef __attribute__((ext_vector_type(4))) float f32x4;

__device__ __forceinline__ unsigned short f2bf(float f){
  unsigned int u = __float_as_uint(f);
  unsigned int r = (u + 0x7FFFu + ((u >> 16) & 1u)) >> 16;   // RNE
  return (unsigned short)r;
}
__device__ __forceinline__ float bf2f(unsigned int b){
  return __uint_as_float(b << 16);
}

// ---------------- CSR build ----------------

__global__ void k_zero(int* __restrict__ p, int n){
  int i = blockIdx.x*256 + threadIdx.x;
  if(i < n) p[i] = 0;
}

__global__ __launch_bounds__(256) void k_bhist(const int* __restrict__ dst, int E,
                                               int* __restrict__ bcnt, int NB){
  __shared__ int l[MAXNB];
  int t = threadIdx.x;
  int base = blockIdx.x*HIST_CHUNK;
  int end = base + HIST_CHUNK; if(end > E) end = E;
  for(int b = t; b < NB; b += 256) l[b] = 0;
  __syncthreads();
  for(int i = base + t; i < end; i += 256) atomicAdd(&l[dst[i] >> BSH], 1);
  __syncthreads();
  for(int b = t; b < NB; b += 256){ int c = l[b]; if(c) atomicAdd(&bcnt[b], c); }
}

__global__ void k_bscan(const int* __restrict__ bcnt, int* __restrict__ bofs,
                        int* __restrict__ bcur, int NB, int E){
  __shared__ int sh[1024];
  int t = threadIdx.x;
  int c0 = (2*t   < NB) ? bcnt[2*t]   : 0;
  int c1 = (2*t+1 < NB) ? bcnt[2*t+1] : 0;
  sh[t] = c0 + c1; __syncthreads();
  for(int off = 1; off < 1024; off <<= 1){
    int v = (t >= off) ? sh[t - off] : 0;
    __syncthreads();
    sh[t] += v;
    __syncthreads();
  }
  int pairEx = sh[t] - (c0 + c1);
  if(2*t   < NB){ bofs[2*t]   = pairEx;      bcur[2*t]   = pairEx; }
  if(2*t+1 < NB){ bofs[2*t+1] = pairEx + c0; bcur[2*t+1] = pairEx + c0; }
  if(t == 0) bofs[NB] = E;
}

__global__ __launch_bounds__(256) void k_binpass(const int* __restrict__ src,
                          const int* __restrict__ dst, int E,
                          int* __restrict__ bcur, unsigned int* __restrict__ binned, int NB){
  __shared__ int lcnt[MAXNB];
  __shared__ int lpos[MAXNB];
  int t = threadIdx.x;
  int base = blockIdx.x * BIN_CHUNK;
  int end = base + BIN_CHUNK; if(end > E) end = E;
  for(int b = t; b < NB; b += 256) lcnt[b] = 0;
  __syncthreads();
  for(int i = base + t; i < end; i += 256)
    atomicAdd(&lcnt[dst[i] >> BSH], 1);
  __syncthreads();
  for(int b = t; b < NB; b += 256){
    int c = lcnt[b];
    lpos[b] = c ? atomicAdd(&bcur[b], c) : 0;
  }
  __syncthreads();
  for(int i = base + t; i < end; i += 256){
    int d = dst[i];
    int b = d >> BSH;
    unsigned int rec = (unsigned int)src[i] | ((unsigned int)(d & (NPB-1)) << 17);
    int p = atomicAdd(&lpos[b], 1);
    binned[p] = rec;
  }
}

__global__ __launch_bounds__(256) void k_bscatter(const unsigned int* __restrict__ binned,
     const int* __restrict__ bofs, int* __restrict__ csr, int* __restrict__ row_ofs,
     float* __restrict__ dinv, int N, int E, int NB){
  __shared__ int lcnt[NPB];
  __shared__ int lofs[NPB];
  __shared__ int lcur[NPB];
  int b = blockIdx.x, t = threadIdx.x;
  int beg = bofs[b], end = bofs[b+1];
  if(t < NPB) lcnt[t] = 0;
  __syncthreads();
  for(int i = beg + t; i < end; i += 256) atomicAdd(&lcnt[binned[i] >> 17], 1);
  __syncthreads();
  if(t < NPB){   // wave 0 only
    int c = lcnt[t];
    int v = c;
    #pragma unroll
    for(int off = 1; off < 64; off <<= 1){
      int nv = __shfl_up(v, off, 64);
      if(t >= off) v += nv;
    }
    int ex = v - c;
    lofs[t] = beg + ex; lcur[t] = 0;
    int node = (b << BSH) + t;
    if(node < N){
      row_ofs[node] = beg + ex;
      dinv[node] = rsqrtf((float)(c + 1));   // +1 self loop
    }
  }
  __syncthreads();
  for(int i = beg + t; i < end; i += 256){
    unsigned int rec = binned[i];
    int dl = rec >> 17;
    int pos = lofs[dl] + atomicAdd(&lcur[dl], 1);
    csr[pos] = (int)(rec & 0x1FFFFu);
  }
  if(b == NB-1 && t == 0) row_ofs[N] = E;
}

// ---------------- GEMM1 (MFMA bf16): g1 = bf16( dinv * (x @ W1) ) ----------------
__global__ __launch_bounds__(256) void k_gemm1(const float* __restrict__ x, const float* __restrict__ W1,
                        const float* __restrict__ dinv, unsigned short* __restrict__ g1, int n){
  __shared__ unsigned short xs[64*136];   // x tile, bf16 [node][k]
  __shared__ unsigned short wt[64*136];   // W1^T,   bf16 [nout][k]
  int tid = threadIdx.x;
  int nodeBase = blockIdx.x*64;
  {
    const float4* x4 = (const float4*)x;
    for(int i = tid; i < 2048; i += 256){
      int node = i >> 5, kg = i & 31;
      float4 v = make_float4(0.f,0.f,0.f,0.f);
      if(nodeBase + node < n) v = x4[(size_t)(nodeBase + node)*32 + kg];
      unsigned p0 = (unsigned)f2bf(v.x) | ((unsigned)f2bf(v.y) << 16);
      unsigned p1 = (unsigned)f2bf(v.z) | ((unsigned)f2bf(v.w) << 16);
      *(uint2*)&xs[node*136 + kg*4] = make_uint2(p0, p1);
    }
  }
  {
    for(int i = tid; i < 2048; i += 256){
      int nn = i >> 5, kq = i & 31;
      unsigned short q0 = f2bf(W1[(kq*4+0)*64 + nn]);
      unsigned short q1 = f2bf(W1[(kq*4+1)*64 + nn]);
      unsigned short q2 = f2bf(W1[(kq*4+2)*64 + nn]);
      unsigned short q3 = f2bf(W1[(kq*4+3)*64 + nn]);
      unsigned p0 = (unsigned)q0 | ((unsigned)q1 << 16);
      unsigned p1 = (unsigned)q2 | ((unsigned)q3 << 16);
      *(uint2*)&wt[nn*136 + kq*4] = make_uint2(p0, p1);
    }
  }
  __syncthreads();

  int w = tid >> 6, lane = tid & 63;
  int ml = lane & 15, q = lane >> 4;
  f32x4 acc0 = {0.f,0.f,0.f,0.f}, acc1 = {0.f,0.f,0.f,0.f},
        acc2 = {0.f,0.f,0.f,0.f}, acc3 = {0.f,0.f,0.f,0.f};
  const unsigned short* arow = &xs[(w*16 + ml)*136 + q*8];
  const unsigned short* brow = &wt[ml*136 + q*8];
  #pragma unroll
  for(int s = 0; s < 4; s++){
    bf16x8 a = *(const bf16x8*)(arow + s*32);
    bf16x8 b0 = *(const bf16x8*)(brow +   0*136 + s*32);
    bf16x8 b1 = *(const bf16x8*)(brow +  16*136 + s*32);
    bf16x8 b2 = *(const bf16x8*)(brow +  32*136 + s*32);
    bf16x8 b3 = *(const bf16x8*)(brow +  48*136 + s*32);
    acc0 = __builtin_amdgcn_mfma_f32_16x16x32_bf16(a, b0, acc0, 0, 0, 0);
    acc1 = __builtin_amdgcn_mfma_f32_16x16x32_bf16(a, b1, acc1, 0, 0, 0);
    acc2 = __builtin_amdgcn_mfma_f32_16x16x32_bf16(a, b2, acc2, 0, 0, 0);
    acc3 = __builtin_amdgcn_mfma_f32_16x16x32_bf16(a, b3, acc3, 0, 0, 0);
  }
  int basem = nodeBase + w*16 + q*4;
  #pragma unroll
  for(int r = 0; r < 4; r++){
    int node = basem + r;
    if(node < n){
      float dv = dinv[node];
      g1[(size_t)node*64 +  0 + ml] = f2bf(acc0[r]*dv);
      g1[(size_t)node*64 + 16 + ml] = f2bf(acc1[r]*dv);
      g1[(size_t)node*64 + 32 + ml] = f2bf(acc2[r]*dv);
      g1[(size_t)node*64 + 48 + ml] = f2bf(acc3[r]*dv);
    }
  }
}

// gather inner loop: 16 rows per batch = 8 shfl + 8 dword loads in flight.
// half = lane>>5 handles rows j+2p+half; fl = lane&31 is the dword column.
#define GATHER_BODY(G32)                                                          \
  for(int e = beg; e < end; e += 64){                                             \
    int cnt = end - e; if(cnt > 64) cnt = 64;                                     \
    int idx = (lane < cnt) ? csr[e + lane] : 0;                                   \
    int j = 0;                                                                    \
    for(; j + 16 <= cnt; j += 16){                                                \
      int i0=__shfl(idx,j+ 0+half,64), i1=__shfl(idx,j+ 2+half,64),               \
          i2=__shfl(idx,j+ 4+half,64), i3=__shfl(idx,j+ 6+half,64),               \
          i4=__shfl(idx,j+ 8+half,64), i5=__shfl(idx,j+10+half,64),               \
          i6=__shfl(idx,j+12+half,64), i7=__shfl(idx,j+14+half,64);               \
      unsigned v0=G32[((unsigned)i0<<5)+fl], v1=G32[((unsigned)i1<<5)+fl],        \
               v2=G32[((unsigned)i2<<5)+fl], v3=G32[((unsigned)i3<<5)+fl],        \
               v4=G32[((unsigned)i4<<5)+fl], v5=G32[((unsigned)i5<<5)+fl],        \
               v6=G32[((unsigned)i6<<5)+fl], v7=G32[((unsigned)i7<<5)+fl];        \
      alo += ((__uint_as_float(v0<<16) + __uint_as_float(v1<<16))                 \
            + (__uint_as_float(v2<<16) + __uint_as_float(v3<<16)))                \
           + ((__uint_as_float(v4<<16) + __uint_as_float(v5<<16))                 \
            + (__uint_as_float(v6<<16) + __uint_as_float(v7<<16)));               \
      ahi += ((__uint_as_float(v0&0xFFFF0000u) + __uint_as_float(v1&0xFFFF0000u)) \
            + (__uint_as_float(v2&0xFFFF0000u) + __uint_as_float(v3&0xFFFF0000u)))\
           + ((__uint_as_float(v4&0xFFFF0000u) + __uint_as_float(v5&0xFFFF0000u)) \
            + (__uint_as_float(v6&0xFFFF0000u) + __uint_as_float(v7&0xFFFF0000u)));\
    }                                                                             \
    if(j < cnt){                                                                  \
      int i0=__shfl(idx,j+ 0+half,64), i1=__shfl(idx,j+ 2+half,64),               \
          i2=__shfl(idx,j+ 4+half,64), i3=__shfl(idx,j+ 6+half,64),               \
          i4=__shfl(idx,j+ 8+half,64), i5=__shfl(idx,j+10+half,64),               \
          i6=__shfl(idx,j+12+half,64), i7=__shfl(idx,j+14+half,64);               \
      unsigned v0=G32[((unsigned)i0<<5)+fl], v1=G32[((unsigned)i1<<5)+fl],        \
               v2=G32[((unsigned)i2<<5)+fl], v3=G32[((unsigned)i3<<5)+fl],        \
               v4=G32[((unsigned)i4<<5)+fl], v5=G32[((unsigned)i5<<5)+fl],        \
               v6=G32[((unsigned)i6<<5)+fl], v7=G32[((unsigned)i7<<5)+fl];        \
      float w0=(j+ 0+half<cnt)?1.f:0.f, w1=(j+ 2+half<cnt)?1.f:0.f,               \
            w2=(j+ 4+half<cnt)?1.f:0.f, w3=(j+ 6+half<cnt)?1.f:0.f,               \
            w4=(j+ 8+half<cnt)?1.f:0.f, w5=(j+10+half<cnt)?1.f:0.f,               \
            w6=(j+12+half<cnt)?1.f:0.f, w7=(j+14+half<cnt)?1.f:0.f;               \
      alo = fmaf(w0, __uint_as_float(v0<<16), alo);                               \
      alo = fmaf(w1, __uint_as_float(v1<<16), alo);                               \
      alo = fmaf(w2, __uint_as_float(v2<<16), alo);                               \
      alo = fmaf(w3, __uint_as_float(v3<<16), alo);                               \
      alo = fmaf(w4, __uint_as_float(v4<<16), alo);                               \
      alo = fmaf(w5, __uint_as_float(v5<<16), alo);                               \
      alo = fmaf(w6, __uint_as_float(v6<<16), alo);                               \
      alo = fmaf(w7, __uint_as_float(v7<<16), alo);                               \
      ahi = fmaf(w0, __uint_as_float(v0&0xFFFF0000u), ahi);                       \
      ahi = fmaf(w1, __uint_as_float(v1&0xFFFF0000u), ahi);                       \
      ahi = fmaf(w2, __uint_as_float(v2&0xFFFF0000u), ahi);                       \
      ahi = fmaf(w3, __uint_as_float(v3&0xFFFF0000u), ahi);                       \
      ahi = fmaf(w4, __uint_as_float(v4&0xFFFF0000u), ahi);                       \
      ahi = fmaf(w5, __uint_as_float(v5&0xFFFF0000u), ahi);                       \
      ahi = fmaf(w6, __uint_as_float(v6&0xFFFF0000u), ahi);                       \
      ahi = fmaf(w7, __uint_as_float(v7&0xFFFF0000u), ahi);                       \
    }                                                                             \
  }

// ---------------- agg1: u = bf16( dinv * relu( dinv*(self + sum) + b1 ) ) ----------------
__global__ __launch_bounds__(256) void k_agg1(const unsigned short* __restrict__ g1,
    const int* __restrict__ row_ofs, const int* __restrict__ csr,
    const float* __restrict__ dinv, const float* __restrict__ b1,
    unsigned short* __restrict__ u, int N){
  int wid = threadIdx.x >> 6, lane = threadIdx.x & 63;
  int half = lane >> 5, fl = lane & 31;
  int node = blockIdx.x*4 + wid;
  if(node >= N) return;
  int beg = row_ofs[node], end = row_ofs[node+1];
  const unsigned* g32 = (const unsigned*)g1;
  float alo = 0.f, ahi = 0.f;
  if(half == 0){   // self-loop row, added once
    unsigned v = g32[((unsigned)node << 5) + fl];
    alo = __uint_as_float(v << 16);
    ahi = __uint_as_float(v & 0xFFFF0000u);
  }
  GATHER_BODY(g32)
  alo += __shfl_xor(alo, 32, 64);
  ahi += __shfl_xor(ahi, 32, 64);
  float dv = dinv[node];
  float2 bb = ((const float2*)b1)[fl];
  float h0 = fmaxf(fmaf(dv, alo, bb.x), 0.f);
  float h1 = fmaxf(fmaf(dv, ahi, bb.y), 0.f);
  if(half == 0){
    unsigned p = (unsigned)f2bf(dv*h0) | ((unsigned)f2bf(dv*h1) << 16);
    *(unsigned*)&u[((size_t)node << 6) + fl*2] = p;
  }
}

// ---------------- GEMM2: g2 = bf16( u @ W2 ), rows padded to 64 ----------------
__global__ __launch_bounds__(256) void k_gemm2(const unsigned short* __restrict__ u,
                        const float* __restrict__ W2, unsigned short* __restrict__ g2, int n){
  __shared__ float hs[64*65];
  __shared__ float ws[64*40];
  int t = threadIdx.x;
  int nodeBase = blockIdx.x*64;
  for(int i = t; i < 2560; i += 256) ws[i] = W2[i];
  for(int i = t; i < 512; i += 256){
    int row = i >> 3, seg = i & 7;
    uint4 v = make_uint4(0,0,0,0);
    if(nodeBase + row < n) v = *(const uint4*)&u[(size_t)(nodeBase + row)*64 + seg*8];
    float* dp = &hs[row*65 + seg*8];
    dp[0]=bf2f(v.x&0xFFFFu); dp[1]=bf2f(v.x>>16);
    dp[2]=bf2f(v.y&0xFFFFu); dp[3]=bf2f(v.y>>16);
    dp[4]=bf2f(v.z&0xFFFFu); dp[5]=bf2f(v.z>>16);
    dp[6]=bf2f(v.w&0xFFFFu); dp[7]=bf2f(v.w>>16);
  }
  __syncthreads();
  int tn = t >> 3, tf = t & 7;
  int n0 = tn*2, f0 = tf*5;
  float a2[2][5] = {{0.f,0.f,0.f,0.f,0.f},{0.f,0.f,0.f,0.f,0.f}};
  #pragma unroll 4
  for(int k = 0; k < 64; k++){
    float a0 = hs[(n0+0)*65 + k];
    float a1 = hs[(n0+1)*65 + k];
    float w0 = ws[k*40+f0+0], w1 = ws[k*40+f0+1], w2 = ws[k*40+f0+2],
          w3 = ws[k*40+f0+3], w4 = ws[k*40+f0+4];
    a2[0][0]+=a0*w0; a2[0][1]+=a0*w1; a2[0][2]+=a0*w2; a2[0][3]+=a0*w3; a2[0][4]+=a0*w4;
    a2[1][0]+=a1*w0; a2[1][1]+=a1*w1; a2[1][2]+=a1*w2; a2[1][3]+=a1*w3; a2[1][4]+=a1*w4;
  }
  #pragma unroll
  for(int i = 0; i < 2; i++){
    int node = nodeBase + n0 + i;
    if(node < n){
      #pragma unroll
      for(int j = 0; j < 5; j++)
        g2[(size_t)node*64 + f0 + j] = f2bf(a2[i][j]);
    }
  }
}

// ---------------- agg2 + bias + log_softmax (2 classes/lane) ----------------
__global__ __launch_bounds__(256) void k_agg2(const unsigned short* __restrict__ g2,
     const int* __restrict__ row_ofs, const int* __restrict__ csr,
     const float* __restrict__ dinv, const float* __restrict__ b2,
     float* __restrict__ out, int N){
  int wid = threadIdx.x >> 6, lane = threadIdx.x & 63;
  int half = lane >> 5, fl = lane & 31;
  int node = blockIdx.x*4 + wid;
  if(node >= N) return;
  int beg = row_ofs[node], end = row_ofs[node+1];
  const unsigned* g32 = (const unsigned*)g2;
  float alo = 0.f, ahi = 0.f;
  if(half == 0){   // self row
    unsigned v = g32[((unsigned)node << 5) + fl];
    alo = __uint_as_float(v << 16);
    ahi = __uint_as_float(v & 0xFFFF0000u);
  }
  GATHER_BODY(g32)
  alo += __shfl_xor(alo, 32, 64);
  ahi += __shfl_xor(ahi, 32, 64);
  float dv = dinv[node];
  bool valid = (fl < 20);   // classes 2fl, 2fl+1 < 40
  float vlo = -INFINITY, vhi = -INFINITY;
  if(valid){
    float2 bb = ((const float2*)b2)[fl];
    vlo = fmaf(dv, alo, bb.x);
    vhi = fmaf(dv, ahi, bb.y);
  }
  float m = fmaxf(vlo, vhi);
  #pragma unroll
  for(int off = 32; off > 0; off >>= 1) m = fmaxf(m, __shfl_xor(m, off, 64));
  float ex = (valid && half == 0) ? (expf(vlo - m) + expf(vhi - m)) : 0.f;
  #pragma unroll
  for(int off = 32; off > 0; off >>= 1) ex += __shfl_xor(ex, off, 64);
  float ll = logf(ex);
  if(valid && half == 0){
    float2 o; o.x = vlo - m - ll; o.y = vhi - m - ll;
    *(float2*)&out[(size_t)node*40 + fl*2] = o;
  }
}

// ---------------- launch ----------------

extern "C" void kernel_launch(void* const* d_in, const int* in_sizes, int n_in,
                              void* d_out, int out_size, void* d_ws, size_t ws_size,
                              hipStream_t stream){
  const float* x  = (const float*)d_in[0];
  const int*   ei = (const int*)  d_in[1];
  const float* W1 = (const float*)d_in[2];
  const float* b1 = (const float*)d_in[3];
  const float* W2 = (const float*)d_in[4];
  const float* b2 = (const float*)d_in[5];
  float* out = (float*)d_out;

  int N = in_sizes[0] / 128;        // 100000
  int E = in_sizes[1] / 2;          // 1600000
  const int* src = ei;
  const int* dst = ei + E;
  int NB = (N + NPB - 1) >> BSH;    // 1563

  char* w = (char*)d_ws;
  auto alloc = [&](size_t bytes) -> char* {
    char* p = w;
    w += (bytes + 511) & ~(size_t)511;
    return p;
  };
  int*   bcnt    = (int*)  alloc((size_t)NB*4);
  int*   bofs    = (int*)  alloc((size_t)(NB+1)*4);
  int*   bcur    = (int*)  alloc((size_t)NB*4);
  int*   row_ofs = (int*)  alloc((size_t)(N+1)*4);
  float* dinv    = (float*)alloc((size_t)N*4);
  unsigned int* binned = (unsigned int*)alloc((size_t)E*4);
  int*   csr     = (int*)  alloc((size_t)E*4);
  unsigned short* g1 = (unsigned short*)alloc((size_t)N*64*2);
  unsigned short* u  = (unsigned short*)alloc((size_t)N*64*2);
  unsigned short* g2 = (unsigned short*)alloc((size_t)N*64*2);

  k_zero    <<<(NB+255)/256, 256, 0, stream>>>(bcnt, NB);
  k_bhist   <<<(E+HIST_CHUNK-1)/HIST_CHUNK, 256, 0, stream>>>(dst, E, bcnt, NB);
  k_bscan   <<<1, 1024, 0, stream>>>(bcnt, bofs, bcur, NB, E);
  k_binpass <<<(E+BIN_CHUNK-1)/BIN_CHUNK, 256, 0, stream>>>(src, dst, E, bcur, binned, NB);
  k_bscatter<<<NB, 256, 0, stream>>>(binned, bofs, csr, row_ofs, dinv, N, E, NB);

  k_gemm1   <<<(N+63)/64, 256, 0, stream>>>(x, W1, dinv, g1, N);
  k_agg1    <<<(N+3)/4, 256, 0, stream>>>(g1, row_ofs, csr, dinv, b1, u, N);
  k_gemm2   <<<(N+63)/64, 256, 0, stream>>>(u, W2, g2, N);
  k_agg2    <<<(N+3)/4, 256, 0, stream>>>(g2, row_ofs, csr, dinv, b2, out, N);
}